// Round 3
// baseline (407.116 us; speedup 1.0000x reference)
//
#include <hip/hip_runtime.h>
#include <math.h>

#define B_ROWS 262144
#define PREP_BLOCKS 128
#define MAIN_BLOCKS 1408
#define TOTAL_BLOCKS (PREP_BLOCKS + MAIN_BLOCKS)   // 1536 = 256 CU x 6 resident
#define TILE_ROWS 8
#define N_TILES (B_ROWS / TILE_ROWS)               // 32768 tiles of 8 rows
#define TILE_F4 198                                // 8*99/4 float4 per array
#define MAIN_STREAMS (MAIN_BLOCKS * 4)             // 5632 streams
#define PREP_STREAMS (PREP_BLOCKS * 4)             // 512 streams
#define PREP_TILES_EACH 5
#define MAIN_LIMIT (N_TILES - PREP_STREAMS * PREP_TILES_EACH)  // 30208

// ws uint-cell layout:
//  [0..9]    atomicMax of ~map(x)  -> global per-feature MIN   (memset 0)
//  [10..19]  atomicMax of  map(x)  -> global per-feature MAX   (memset 0)
//  [20] cm, [21] cf  (sex counts, atomicAdd)                   (memset 0)
//  [22] ready-counter (prep minmax done), [23] done-counter    (memset 0)
//  [24..223] hist 100 male + 100 female (integer atomicAdd)    (memset 0)
//  [256..]   C partials: 3 x TOTAL_BLOCKS floats (fully overwritten)
#define WS_HIST 24
#define WS_C 256
#define WS_ZERO_CELLS 224

__device__ __forceinline__ unsigned int map_f(float x) {
  unsigned int b = __float_as_uint(x);
  return (b & 0x80000000u) ? ~b : (b | 0x80000000u);
}
__device__ __forceinline__ float unmap_f(unsigned int u) {
  unsigned int b = (u & 0x80000000u) ? (u ^ 0x80000000u) : ~u;
  return __uint_as_float(b);
}
__device__ __forceinline__ unsigned int aload(const unsigned int* p) {
  return __hip_atomic_load(p, __ATOMIC_RELAXED, __HIP_MEMORY_SCOPE_AGENT);
}
__device__ __forceinline__ float aloadf(const float* p) {
  return __hip_atomic_load(p, __ATOMIC_RELAXED, __HIP_MEMORY_SCOPE_AGENT);
}

// Issue one 8-row tile: d -> LDS via 4 global_load_lds (3 full + lane<6 tail),
// t -> 4 float4 registers (3 full + clamped tail). Exactly 8 vmem instructions
// per call for every wave (exec never 0 on the masked tail).
__device__ __forceinline__ void issue_tile(const float* __restrict__ d,
                                           const float* __restrict__ t,
                                           int tile, int lane, float* lb,
                                           float4& r0, float4& r1,
                                           float4& r2, float4& r3) {
  const float4* dsp = (const float4*)d + (size_t)tile * TILE_F4;
  const float4* tsp = (const float4*)t + (size_t)tile * TILE_F4;
#pragma unroll
  for (int it = 0; it < 3; ++it)
    __builtin_amdgcn_global_load_lds(
        (const __attribute__((address_space(1))) void*)(dsp + it * 64 + lane),
        (__attribute__((address_space(3))) void*)(lb + it * 256), 16, 0, 0);
  if (lane < 6)
    __builtin_amdgcn_global_load_lds(
        (const __attribute__((address_space(1))) void*)(dsp + 192 + lane),
        (__attribute__((address_space(3))) void*)(lb + 768), 16, 0, 0);
  r0 = tsp[lane];
  r1 = tsp[64 + lane];
  r2 = tsp[128 + lane];
  r3 = tsp[192 + ((lane < 6) ? lane : 0)];   // clamped; garbage lanes unused
}

// Round-0-proven per-tile compute: mse/dot (d from LDS b128, t from regs),
// then 16-lane LSE with inline __expf (2 lanes/row, split at col 51).
__device__ __forceinline__ void compute_tile(const float* ldsd,
                                             float4 tv0, float4 tv1,
                                             float4 tv2, float4 tv3, int lane,
                                             float& mse, float& dot, float& ce) {
  const float4* ld4 = (const float4*)ldsd;
  float4 tvv[4] = {tv0, tv1, tv2, tv3};
#pragma unroll
  for (int it = 0; it < 4; ++it) {
    int f = it * 64 + lane;
    if (f < TILE_F4) {
      float4 xd = ld4[f];
      float4 xt = tvv[it];
      int e = f * 4;
      int c = e - (e / 99) * 99;             // magic-mul const divisor
      float dv[4] = {xd.x, xd.y, xd.z, xd.w};
      float tw[4] = {xt.x, xt.y, xt.z, xt.w};
#pragma unroll
      for (int k = 0; k < 4; k++) {
        int cc = c + k;
        if (cc >= 99) cc -= 99;
        bool cont = (cc == 0) | ((unsigned)(cc - 55) <= 2u);
        float diff = dv[k] - tw[k];
        if (cont) mse += diff * diff;
        else      dot += tw[k] * dv[k];
      }
    }
  }
  if (lane < 2 * TILE_ROWS) {
    const float* row = ldsd + (lane >> 1) * 99;
    float Z;
    if ((lane & 1) == 0) {                // blocks (1,8)(8,24)(24,31)(31,45)(45,51)
      Z = 0.f;
#pragma unroll
      for (int c = 1; c < 8; c++) Z += __expf(row[c]);
      ce += __logf(Z);
      Z = 0.f;
#pragma unroll
      for (int c = 8; c < 24; c++) Z += __expf(row[c]);
      ce += __logf(Z);
      Z = 0.f;
#pragma unroll
      for (int c = 24; c < 31; c++) Z += __expf(row[c]);
      ce += __logf(Z);
      Z = 0.f;
#pragma unroll
      for (int c = 31; c < 45; c++) Z += __expf(row[c]);
      ce += __logf(Z);
      Z = 0.f;
#pragma unroll
      for (int c = 45; c < 51; c++) Z += __expf(row[c]);
      ce += __logf(Z);
    } else {                              // blocks (51,53)(53,55)(58,99)
      Z = 0.f;
#pragma unroll
      for (int c = 51; c < 53; c++) Z += __expf(row[c]);
      ce += __logf(Z);
      Z = 0.f;
#pragma unroll
      for (int c = 53; c < 55; c++) Z += __expf(row[c]);
      ce += __logf(Z);
      Z = 0.f;
#pragma unroll
      for (int c = 58; c < 99; c++) Z += __expf(row[c]);
      ce += __logf(Z);
    }
  }
}

// Ping-pong streaming: manual 2x unroll so registers/buffers alternate roles
// with NO cross-iteration copies and NO conditional loads (last iteration
// prefetches a clamped-valid tile whose results are simply unused).
// vmcnt invariant: 8 outstanding at loop top; issue 8 more; vmcnt(8) drains
// the current tile's 8 (oldest; vmem retires in order).
__device__ __forceinline__ void stream_tiles(const float* __restrict__ d,
                                             const float* __restrict__ t,
                                             float* lb0, float* lb1,
                                             int start, int stride, int limit,
                                             int lane,
                                             float& mse, float& dot, float& ce) {
  float4 a0, a1, a2, a3, b0, b1, b2, b3;
  int tile = start;
  issue_tile(d, t, tile, lane, lb0, a0, a1, a2, a3);
  for (;;) {
    int next = tile + stride;
    bool last = next >= limit;
    issue_tile(d, t, last ? start : next, lane, lb1, b0, b1, b2, b3);
    asm volatile("s_waitcnt vmcnt(8)" ::: "memory");
    __builtin_amdgcn_sched_barrier(0);
    compute_tile(lb0, a0, a1, a2, a3, lane, mse, dot, ce);
    if (last) break;
    tile = next;
    next = tile + stride;
    last = next >= limit;
    issue_tile(d, t, last ? start : next, lane, lb0, a0, a1, a2, a3);
    asm volatile("s_waitcnt vmcnt(8)" ::: "memory");
    __builtin_amdgcn_sched_barrier(0);
    compute_tile(lb1, b0, b1, b2, b3, lane, mse, dot, ce);
    if (last) break;
    tile = next;
  }
}

__global__ __launch_bounds__(256, 6) void k_fused(const float* __restrict__ enc,
                                                  const float* __restrict__ d,
                                                  const float* __restrict__ t,
                                                  unsigned int* __restrict__ ws,
                                                  float* __restrict__ out) {
  __shared__ float sd[4][2][800];     // per-wave ping-pong d tiles (25.6 KB)
  __shared__ float red[16];
  __shared__ float mnv[10], wid[10];
  __shared__ unsigned int h[200];
  __shared__ float smn[4][10], smx[4][10];
  __shared__ unsigned int sc[4][2];
  __shared__ int lastflag;

  int tid = threadIdx.x, bid = blockIdx.x;
  int wave = tid >> 6, lane = tid & 63;
  float* lb0 = sd[wave][0];
  float* lb1 = sd[wave][1];

  float mse = 0.f, dot = 0.f, ce = 0.f;

  if (bid < PREP_BLOCKS) {
    // ---------- prep pass 1: minmax + sex counts over data_encoded ----------
    const float4* e4 = (const float4*)enc;
    float mn[10], mx[10];
#pragma unroll
    for (int j = 0; j < 10; j++) { mn[j] = 1e30f; mx[j] = -1e30f; }
    unsigned int cm = 0, cf = 0;
#pragma unroll
    for (int i = 0; i < 8; i++) {
      size_t g = (size_t)bid * 2048 + i * 256 + tid;
      float4 a = e4[g * 3 + 0], b = e4[g * 3 + 1], c = e4[g * 3 + 2];
      float v[12] = {a.x,a.y,a.z,a.w,b.x,b.y,b.z,b.w,c.x,c.y,c.z,c.w};
#pragma unroll
      for (int j = 0; j < 10; j++) { mn[j] = fminf(mn[j], v[j]); mx[j] = fmaxf(mx[j], v[j]); }
      cm += (v[11] == 0.0f); cf += (v[11] == 1.0f);
    }
#pragma unroll
    for (int off = 32; off; off >>= 1) {
#pragma unroll
      for (int j = 0; j < 10; j++) {
        mn[j] = fminf(mn[j], __shfl_xor(mn[j], off));
        mx[j] = fmaxf(mx[j], __shfl_xor(mx[j], off));
      }
      cm += __shfl_xor(cm, off); cf += __shfl_xor(cf, off);
    }
    if (lane == 0) {
#pragma unroll
      for (int j = 0; j < 10; j++) { smn[wave][j] = mn[j]; smx[wave][j] = mx[j]; }
      sc[wave][0] = cm; sc[wave][1] = cf;
    }
    __syncthreads();
    if (tid < 10) {
      float m = fminf(fminf(smn[0][tid], smn[1][tid]), fminf(smn[2][tid], smn[3][tid]));
      atomicMax(ws + tid, ~map_f(m));          // min via max of ~map, init 0
    } else if (tid < 20) {
      int j = tid - 10;
      float m = fmaxf(fmaxf(smx[0][j], smx[1][j]), fmaxf(smx[2][j], smx[3][j]));
      atomicMax(ws + tid, map_f(m));
    } else if (tid < 22) {
      int j = tid - 20;
      atomicAdd(ws + 20 + j, sc[0][j] + sc[1][j] + sc[2][j] + sc[3][j]);
    }
    __syncthreads();                           // drains this block's atomics
    if (tid == 0) {
      __threadfence();
      __hip_atomic_fetch_add(ws + 22, 1u, __ATOMIC_ACQ_REL, __HIP_MEMORY_SCOPE_AGENT);
    }
    // ---------- prep streams its 5-tile share (no gate on this path) --------
    int pw = bid * 4 + wave;
    stream_tiles(d, t, lb0, lb1, MAIN_LIMIT + pw, PREP_STREAMS, N_TILES,
                 lane, mse, dot, ce);
    // ---------- gate AFTER streaming (all prep blocks incremented long ago;
    // deadlock-free: main blocks never wait, grid == resident capacity) ------
    if (tid == 0) {
      while (__hip_atomic_load(ws + 22, __ATOMIC_ACQUIRE, __HIP_MEMORY_SCOPE_AGENT)
             < PREP_BLOCKS)
        __builtin_amdgcn_s_sleep(2);
    }
    __syncthreads();
    // ---------- prep pass 2: histogram with global min/max (enc L3-hot) -----
    if (tid < 10) {
      unsigned int nm = aload(ws + tid);
      unsigned int xm = aload(ws + 10 + tid);
      float mn_ = unmap_f(~nm);
      mnv[tid] = mn_;
      wid[tid] = fmaxf(unmap_f(xm) - mn_, 1e-12f);
    }
    for (int i = tid; i < 200; i += 256) h[i] = 0u;
    __syncthreads();
#pragma unroll
    for (int i = 0; i < 8; i++) {
      size_t g = (size_t)bid * 2048 + i * 256 + tid;
      float4 a = e4[g * 3 + 0], b = e4[g * 3 + 1], c = e4[g * 3 + 2];
      float v[12] = {a.x,a.y,a.z,a.w,b.x,b.y,b.z,b.w,c.x,c.y,c.z,c.w};
      int base = (v[11] == 0.0f) ? 0 : ((v[11] == 1.0f) ? 100 : -1);
      if (base >= 0) {
#pragma unroll
        for (int cc2 = 0; cc2 < 10; cc2++) {
          float tt = (v[cc2] - mnv[cc2]) / wid[cc2] * 10.0f;   // reference op order
          int bi = min(max((int)floorf(tt), 0), 9);
          atomicAdd(&h[base + cc2 * 10 + bi], 1u);
        }
      }
    }
    __syncthreads();
    if (tid < 200) atomicAdd(ws + WS_HIST + tid, h[tid]);      // deterministic
  } else {
    // ---------- main: ~5.4-tile streams (round-0 proven geometry) -----------
    int gw = (bid - PREP_BLOCKS) * 4 + wave;
    stream_tiles(d, t, lb0, lb1, gw, MAIN_STREAMS, MAIN_LIMIT,
                 lane, mse, dot, ce);
  }

  // ---------- per-block reduction of streamed partials (all 1536 blocks) ----
#pragma unroll
  for (int off = 32; off; off >>= 1) {
    mse += __shfl_xor(mse, off);
    dot += __shfl_xor(dot, off);
    ce  += __shfl_xor(ce,  off);
  }
  if (lane == 0) { red[wave] = mse; red[4 + wave] = dot; red[8 + wave] = ce; }
  __syncthreads();
  if (tid == 0) {
    float* C = (float*)(ws + WS_C);
    C[bid]                    = red[0] + red[1] + red[2]  + red[3];
    C[TOTAL_BLOCKS + bid]     = red[4] + red[5] + red[6]  + red[7];
    C[2 * TOTAL_BLOCKS + bid] = red[8] + red[9] + red[10] + red[11];
  }

  // ---------- done-counter election; globally-last block finalizes ----------
  __syncthreads();
  if (tid == 0) {
    __threadfence();
    unsigned int old = __hip_atomic_fetch_add(ws + 23, 1u, __ATOMIC_ACQ_REL,
                                              __HIP_MEMORY_SCOPE_AGENT);
    lastflag = (old == (unsigned int)(TOTAL_BLOCKS - 1)) ? 1 : 0;
  }
  __syncthreads();
  if (lastflag == 0) return;
  __threadfence();

  const float* C = (const float*)(ws + WS_C);
  float msum = 0.f, dsum = 0.f, csum = 0.f;
  for (int i = tid; i < TOTAL_BLOCKS; i += 256) {
    msum += aloadf(C + i);
    dsum += aloadf(C + TOTAL_BLOCKS + i);
    csum += aloadf(C + 2 * TOTAL_BLOCKS + i);
  }
  float term = 0.f;
  if (tid < 100) {
    float cmf = fmaxf((float)aload(ws + 20), 1.0f);
    float cff = fmaxf((float)aload(ws + 21), 1.0f);
    float mc = (float)aload(ws + WS_HIST + tid);
    float fc = (float)aload(ws + WS_HIST + 100 + tid);
    if (mc > 0.f && fc > 0.f) {
      float pp = mc / cmf, qq = fc / cff;
      term = pp * logf(pp / qq);
    }
  }
#pragma unroll
  for (int off = 32; off; off >>= 1) {
    msum += __shfl_xor(msum, off);
    dsum += __shfl_xor(dsum, off);
    csum += __shfl_xor(csum, off);
    term += __shfl_xor(term, off);
  }
  if (lane == 0) {
    red[wave] = msum; red[4 + wave] = dsum; red[8 + wave] = csum; red[12 + wave] = term;
  }
  __syncthreads();
  if (tid == 0) {
    const float invB = 1.0f / (float)B_ROWS;
    float mse_ = (red[0] + red[1] + red[2] + red[3]) * invB;
    float dd   = red[4] + red[5] + red[6] + red[7];
    float cc   = red[8] + red[9] + red[10] + red[11];
    float ce_  = (cc - dd) * invB;
    float akld = 0.5f * (red[12] + red[13] + red[14] + red[15]);
    out[0] = 0.5f * (mse_ + ce_) + akld;
    out[1] = mse_;
    out[2] = ce_;
    out[3] = akld;
  }
}

extern "C" void kernel_launch(void* const* d_in, const int* in_sizes, int n_in,
                              void* d_out, int out_size, void* d_ws, size_t ws_size,
                              hipStream_t stream) {
  const float* enc = (const float*)d_in[0];   // data_encoded (B,12)
  const float* dec = (const float*)d_in[1];   // data_decoded (B,99)
  const float* tru = (const float*)d_in[2];   // data_true    (B,99)
  unsigned int* ws = (unsigned int*)d_ws;
  float* out = (float*)d_out;

  hipMemsetAsync(d_ws, 0, WS_ZERO_CELLS * sizeof(unsigned int), stream);
  hipLaunchKernelGGL(k_fused, dim3(TOTAL_BLOCKS), dim3(256), 0, stream,
                     enc, dec, tru, ws, out);
}

// Round 4
// 290.321 us; speedup vs baseline: 1.4023x; 1.4023x over previous
//
#include <hip/hip_runtime.h>
#include <math.h>

#define B_ROWS 262144

// ws layout (4-byte cells), total <= 33024 cells = 132 KB (proven budget):
//  A: minmax partials: 128 x 22  (mapped-uint min[10], max[10], cm, cf)
//  B: hist partials:   128 x 200 at offset 2816
//  C: main partials:   3 x 768   at offset 28416
#define WS_A 0
#define WS_B 2816
#define WS_C 28416
#define MAIN_BLOCKS 768       // 3 blocks/CU resident (51.2 KB LDS each)
#define N_STREAMS (MAIN_BLOCKS * 4)   // 3072 wave streams, ~10.7 tiles each
#define TILE_ROWS 8
#define N_TILES 32768         // 262144 / 8
#define TILE_F4 198           // 8*99/4 float4 per array per tile

__device__ __forceinline__ unsigned int map_f(float x) {
  unsigned int b = __float_as_uint(x);
  return (b & 0x80000000u) ? ~b : (b | 0x80000000u);
}
__device__ __forceinline__ float unmap_f(unsigned int u) {
  unsigned int b = (u & 0x80000000u) ? (u ^ 0x80000000u) : ~u;
  return __uint_as_float(b);
}

// ---------------- pass 1 over data_encoded (verbatim round-0) ----------------
__global__ __launch_bounds__(256) void k_minmax(const float* __restrict__ enc,
                                                unsigned int* __restrict__ ws) {
  int tid = threadIdx.x, bid = blockIdx.x;
  const float4* e4 = (const float4*)enc;
  float mn[10], mx[10];
  #pragma unroll
  for (int j = 0; j < 10; j++) { mn[j] = 1e30f; mx[j] = -1e30f; }
  unsigned int cm = 0, cf = 0;
  #pragma unroll
  for (int i = 0; i < 8; i++) {
    size_t g = (size_t)bid * 2048 + i * 256 + tid;
    float4 a = e4[g * 3 + 0], b = e4[g * 3 + 1], c = e4[g * 3 + 2];
    float v[12] = {a.x,a.y,a.z,a.w,b.x,b.y,b.z,b.w,c.x,c.y,c.z,c.w};
    #pragma unroll
    for (int j = 0; j < 10; j++) { mn[j] = fminf(mn[j], v[j]); mx[j] = fmaxf(mx[j], v[j]); }
    cm += (v[11] == 0.0f); cf += (v[11] == 1.0f);
  }
  #pragma unroll
  for (int off = 32; off; off >>= 1) {
    #pragma unroll
    for (int j = 0; j < 10; j++) {
      mn[j] = fminf(mn[j], __shfl_xor(mn[j], off));
      mx[j] = fmaxf(mx[j], __shfl_xor(mx[j], off));
    }
    cm += __shfl_xor(cm, off); cf += __shfl_xor(cf, off);
  }
  __shared__ float smn[4][10], smx[4][10];
  __shared__ unsigned int sc[4][2];
  int wave = tid >> 6, lane = tid & 63;
  if (lane == 0) {
    #pragma unroll
    for (int j = 0; j < 10; j++) { smn[wave][j] = mn[j]; smx[wave][j] = mx[j]; }
    sc[wave][0] = cm; sc[wave][1] = cf;
  }
  __syncthreads();
  unsigned int* out = ws + WS_A + bid * 22;
  if (tid < 10) {
    float m = fminf(fminf(smn[0][tid], smn[1][tid]), fminf(smn[2][tid], smn[3][tid]));
    out[tid] = map_f(m);
  } else if (tid < 20) {
    int j = tid - 10;
    float m = fmaxf(fmaxf(smx[0][j], smx[1][j]), fmaxf(smx[2][j], smx[3][j]));
    out[tid] = map_f(m);
  } else if (tid < 22) {
    int j = tid - 20;
    out[tid] = sc[0][j] + sc[1][j] + sc[2][j] + sc[3][j];
  }
}

// ---------------- pass 2 over data_encoded: histograms (verbatim round-0) ----
__global__ __launch_bounds__(256) void k_hist(const float* __restrict__ enc,
                                              unsigned int* __restrict__ ws) {
  __shared__ float mnv[10], wid[10];
  __shared__ unsigned int h[200];
  int tid = threadIdx.x, bid = blockIdx.x;
  for (int i = tid; i < 200; i += 256) h[i] = 0u;
  if (tid < 10) {
    unsigned int umn = 0xFFFFFFFFu, umx = 0u;
    #pragma unroll 4
    for (int b = 0; b < 128; b++) {
      umn = min(umn, ws[WS_A + b * 22 + tid]);
      umx = max(umx, ws[WS_A + b * 22 + 10 + tid]);
    }
    float mn = unmap_f(umn);
    mnv[tid] = mn;
    wid[tid] = fmaxf(unmap_f(umx) - mn, 1e-12f);
  }
  __syncthreads();
  const float4* e4 = (const float4*)enc;
  #pragma unroll
  for (int i = 0; i < 8; i++) {
    size_t g = (size_t)bid * 2048 + i * 256 + tid;
    float4 a = e4[g * 3 + 0], b = e4[g * 3 + 1], c = e4[g * 3 + 2];
    float v[12] = {a.x,a.y,a.z,a.w,b.x,b.y,b.z,b.w,c.x,c.y,c.z,c.w};
    int base = (v[11] == 0.0f) ? 0 : ((v[11] == 1.0f) ? 100 : -1);
    if (base >= 0) {
      #pragma unroll
      for (int cc = 0; cc < 10; cc++) {
        float t = (v[cc] - mnv[cc]) / wid[cc] * 10.0f;  // reference op order
        int bi = min(max((int)floorf(t), 0), 9);
        atomicAdd(&h[base + cc * 10 + bi], 1u);
      }
    }
  }
  __syncthreads();
  if (tid < 200) ws[WS_B + bid * 200 + tid] = h[tid];
}

// ---------------- main pass: 12 wave-streams/CU, true double-buffer ----------
// ALL staging is global_load_lds DMA (d AND t) -> no load-result VGPRs cross
// the loop (no spill possible, no compiler-inserted conservative vmcnt).
// 8 DMA instructions per tile; pipeline invariant: issue next tile's 8, then
// vmcnt(8) drains exactly the current tile's 8 (oldest; vmem retires in order).
__device__ __forceinline__ void issue_tile(const float* __restrict__ d,
                                           const float* __restrict__ t,
                                           int tile, int lane,
                                           float* bd, float* bt) {
  const float4* dsp = (const float4*)d + (size_t)tile * TILE_F4;
  const float4* tsp = (const float4*)t + (size_t)tile * TILE_F4;
  #pragma unroll
  for (int it = 0; it < 3; ++it) {
    __builtin_amdgcn_global_load_lds(
        (const __attribute__((address_space(1))) void*)(dsp + it * 64 + lane),
        (__attribute__((address_space(3))) void*)(bd + it * 256), 16, 0, 0);
    __builtin_amdgcn_global_load_lds(
        (const __attribute__((address_space(1))) void*)(tsp + it * 64 + lane),
        (__attribute__((address_space(3))) void*)(bt + it * 256), 16, 0, 0);
  }
  if (lane < 6) {
    __builtin_amdgcn_global_load_lds(
        (const __attribute__((address_space(1))) void*)(dsp + 192 + lane),
        (__attribute__((address_space(3))) void*)(bd + 768), 16, 0, 0);
    __builtin_amdgcn_global_load_lds(
        (const __attribute__((address_space(1))) void*)(tsp + 192 + lane),
        (__attribute__((address_space(3))) void*)(bt + 768), 16, 0, 0);
  }
}

// Round-0-proven per-tile compute, with t now read from LDS as well.
__device__ __forceinline__ void compute_tile(const float* bd, const float* bt,
                                             int lane,
                                             float& mse, float& dot, float& ce) {
  const float4* ld4 = (const float4*)bd;
  const float4* lt4 = (const float4*)bt;
  #pragma unroll
  for (int it = 0; it < 4; ++it) {
    int f = it * 64 + lane;
    if (f < TILE_F4) {
      float4 xd = ld4[f];
      float4 xt = lt4[f];
      int e = f * 4;
      int c = e - (e / 99) * 99;             // magic-mul const divisor
      float dv[4] = {xd.x, xd.y, xd.z, xd.w};
      float tw[4] = {xt.x, xt.y, xt.z, xt.w};
      #pragma unroll
      for (int k = 0; k < 4; k++) {
        int cc = c + k;
        if (cc >= 99) cc -= 99;
        bool cont = (cc == 0) | ((unsigned)(cc - 55) <= 2u);
        float diff = dv[k] - tw[k];
        if (cont) mse += diff * diff;
        else      dot += tw[k] * dv[k];
      }
    }
  }
  // LSE: 2 lanes/row, split at col 51 (a CE-block boundary); 44/45 exps.
  if (lane < 2 * TILE_ROWS) {
    const float* row = bd + (lane >> 1) * 99;
    float Z;
    if ((lane & 1) == 0) {                // blocks (1,8)(8,24)(24,31)(31,45)(45,51)
      Z = 0.f;
      #pragma unroll
      for (int c = 1; c < 8; c++) Z += __expf(row[c]);
      ce += __logf(Z);
      Z = 0.f;
      #pragma unroll
      for (int c = 8; c < 24; c++) Z += __expf(row[c]);
      ce += __logf(Z);
      Z = 0.f;
      #pragma unroll
      for (int c = 24; c < 31; c++) Z += __expf(row[c]);
      ce += __logf(Z);
      Z = 0.f;
      #pragma unroll
      for (int c = 31; c < 45; c++) Z += __expf(row[c]);
      ce += __logf(Z);
      Z = 0.f;
      #pragma unroll
      for (int c = 45; c < 51; c++) Z += __expf(row[c]);
      ce += __logf(Z);
    } else {                              // blocks (51,53)(53,55)(58,99)
      Z = 0.f;
      #pragma unroll
      for (int c = 51; c < 53; c++) Z += __expf(row[c]);
      ce += __logf(Z);
      Z = 0.f;
      #pragma unroll
      for (int c = 53; c < 55; c++) Z += __expf(row[c]);
      ce += __logf(Z);
      Z = 0.f;
      #pragma unroll
      for (int c = 58; c < 99; c++) Z += __expf(row[c]);
      ce += __logf(Z);
    }
  }
}

__global__ __launch_bounds__(256, 3) void k_main(const float* __restrict__ d,
                                                 const float* __restrict__ t,
                                                 unsigned int* __restrict__ ws) {
  __shared__ float sd[4][2][2][800];    // [wave][pingpong][d/t][800] = 51.2 KB
  __shared__ float red[12];
  int tid = threadIdx.x, bid = blockIdx.x;
  int wave = tid >> 6, lane = tid & 63;
  float* base = &sd[wave][0][0][0];     // p stride 1600 floats; t at +800

  float mse = 0.f, dot = 0.f, ce = 0.f;
  int gw = bid * 4 + wave;              // global wave stream id

  int p = 0;
  int tile = gw;
  issue_tile(d, t, tile, lane, base, base + 800);
  while (tile + N_STREAMS < N_TILES) {
    int nx = tile + N_STREAMS;
    float* nb = base + (p ^ 1) * 1600;
    issue_tile(d, t, nx, lane, nb, nb + 800);       // 8 more in flight (16 total)
    asm volatile("s_waitcnt vmcnt(8)" ::: "memory"); // drain current tile only
    __builtin_amdgcn_sched_barrier(0);
    float* cb = base + p * 1600;
    compute_tile(cb, cb + 800, lane, mse, dot, ce);
    // compute's lgkmcnt-waited ds_reads complete before next issue overwrites cb
    p ^= 1;
    tile = nx;
  }
  asm volatile("s_waitcnt vmcnt(0)" ::: "memory");   // epilogue tile
  __builtin_amdgcn_sched_barrier(0);
  {
    float* cb = base + p * 1600;
    compute_tile(cb, cb + 800, lane, mse, dot, ce);
  }

  // ---- block reduction (single barrier AFTER the streaming loop) ----
  #pragma unroll
  for (int off = 32; off; off >>= 1) {
    mse += __shfl_xor(mse, off);
    dot += __shfl_xor(dot, off);
    ce  += __shfl_xor(ce,  off);
  }
  if (lane == 0) { red[wave] = mse; red[4 + wave] = dot; red[8 + wave] = ce; }
  __syncthreads();
  if (tid == 0) {
    float* C = (float*)(ws + WS_C);
    C[bid]                   = red[0] + red[1] + red[2]  + red[3];
    C[MAIN_BLOCKS + bid]     = red[4] + red[5] + red[6]  + red[7];
    C[2 * MAIN_BLOCKS + bid] = red[8] + red[9] + red[10] + red[11];
  }
}

// ---------------- finalize (verbatim round-0, MAIN_BLOCKS=768) ----------------
__global__ __launch_bounds__(256) void k_final(const unsigned int* __restrict__ ws,
                                               float* __restrict__ out) {
  __shared__ float h[200];
  __shared__ float part[256];
  __shared__ float red3[12];
  __shared__ float cnts[2];
  int tid = threadIdx.x;
  if (tid < 200) {
    unsigned int s = 0;
    #pragma unroll 4
    for (int b = 0; b < 128; b++) s += ws[WS_B + b * 200 + tid];
    h[tid] = (float)s;
  }
  if (tid == 200 || tid == 201) {
    unsigned int s = 0;
    #pragma unroll 4
    for (int b = 0; b < 128; b++) s += ws[WS_A + b * 22 + 20 + (tid - 200)];
    cnts[tid - 200] = fmaxf((float)s, 1.0f);
  }
  const float* C = (const float*)(ws + WS_C);
  float msum = 0.f, dsum = 0.f, csum = 0.f;
  for (int i = tid; i < MAIN_BLOCKS; i += 256) {
    msum += C[i]; dsum += C[MAIN_BLOCKS + i]; csum += C[2 * MAIN_BLOCKS + i];
  }
  #pragma unroll
  for (int off = 32; off; off >>= 1) {
    msum += __shfl_xor(msum, off);
    dsum += __shfl_xor(dsum, off);
    csum += __shfl_xor(csum, off);
  }
  int wave = tid >> 6, lane = tid & 63;
  if (lane == 0) { red3[wave] = msum; red3[4 + wave] = dsum; red3[8 + wave] = csum; }
  __syncthreads();
  float term = 0.f;
  if (tid < 100) {
    float mc = h[tid], fc = h[100 + tid];
    if (mc > 0.f && fc > 0.f) {
      float p = mc / cnts[0];
      float q = fc / cnts[1];
      term = p * logf(p / q);
    }
  }
  part[tid] = term;
  __syncthreads();
  for (int s = 128; s; s >>= 1) {
    if (tid < s) part[tid] += part[tid + s];
    __syncthreads();
  }
  if (tid == 0) {
    const float invB = 1.0f / (float)B_ROWS;
    float mse = (red3[0] + red3[1] + red3[2] + red3[3]) * invB;
    float dd  = (red3[4] + red3[5] + red3[6] + red3[7]);
    float cc  = (red3[8] + red3[9] + red3[10] + red3[11]);
    float ce  = (cc - dd) * invB;
    float akld = 0.5f * part[0];
    out[0] = 0.5f * (mse + ce) + akld;
    out[1] = mse;
    out[2] = ce;
    out[3] = akld;
  }
}

extern "C" void kernel_launch(void* const* d_in, const int* in_sizes, int n_in,
                              void* d_out, int out_size, void* d_ws, size_t ws_size,
                              hipStream_t stream) {
  const float* enc = (const float*)d_in[0];   // data_encoded (B,12)
  const float* dec = (const float*)d_in[1];   // data_decoded (B,99)
  const float* tru = (const float*)d_in[2];   // data_true    (B,99)
  unsigned int* ws = (unsigned int*)d_ws;
  float* out = (float*)d_out;

  hipLaunchKernelGGL(k_minmax, dim3(128),         dim3(256), 0, stream, enc, ws);
  hipLaunchKernelGGL(k_hist,   dim3(128),         dim3(256), 0, stream, enc, ws);
  hipLaunchKernelGGL(k_main,   dim3(MAIN_BLOCKS), dim3(256), 0, stream, dec, tru, ws);
  hipLaunchKernelGGL(k_final,  dim3(1),           dim3(256), 0, stream, ws, out);
}

// Round 5
// 277.770 us; speedup vs baseline: 1.4657x; 1.0452x over previous
//
#include <hip/hip_runtime.h>
#include <math.h>

#define B_ROWS 262144

// ws layout (4-byte cells):
//  A: minmax partials: 128 x 22  (mapped-uint min[10], max[10], cm, cf)
//  B: global hist:     200 cells at offset 2816 (int atomicAdd; zeroed by k_minmax)
//  C: main partials:   3 x 1536 at offset 3072
#define WS_A 0
#define WS_B 2816
#define WS_C 3072
#define MAIN_BLOCKS 1536      // 6 blocks/CU resident, 25.6 KB LDS each
#define N_STREAMS (MAIN_BLOCKS * 4)   // 6144 wave streams, ~5.33 tiles each
#define TILE_ROWS 8
#define N_TILES 32768         // 262144 / 8
#define TILE_F4 198           // 8*99/4 float4 per array per tile

__device__ __forceinline__ unsigned int map_f(float x) {
  unsigned int b = __float_as_uint(x);
  return (b & 0x80000000u) ? ~b : (b | 0x80000000u);
}
__device__ __forceinline__ float unmap_f(unsigned int u) {
  unsigned int b = (u & 0x80000000u) ? (u ^ 0x80000000u) : ~u;
  return __uint_as_float(b);
}

// ---------------- pass 1 over data_encoded (r0-proven) ----------------
__global__ __launch_bounds__(256) void k_minmax(const float* __restrict__ enc,
                                                unsigned int* __restrict__ ws) {
  int tid = threadIdx.x, bid = blockIdx.x;
  const float4* e4 = (const float4*)enc;
  float mn[10], mx[10];
  #pragma unroll
  for (int j = 0; j < 10; j++) { mn[j] = 1e30f; mx[j] = -1e30f; }
  unsigned int cm = 0, cf = 0;
  #pragma unroll
  for (int i = 0; i < 8; i++) {
    size_t g = (size_t)bid * 2048 + i * 256 + tid;
    float4 a = e4[g * 3 + 0], b = e4[g * 3 + 1], c = e4[g * 3 + 2];
    float v[12] = {a.x,a.y,a.z,a.w,b.x,b.y,b.z,b.w,c.x,c.y,c.z,c.w};
    #pragma unroll
    for (int j = 0; j < 10; j++) { mn[j] = fminf(mn[j], v[j]); mx[j] = fmaxf(mx[j], v[j]); }
    cm += (v[11] == 0.0f); cf += (v[11] == 1.0f);
  }
  #pragma unroll
  for (int off = 32; off; off >>= 1) {
    #pragma unroll
    for (int j = 0; j < 10; j++) {
      mn[j] = fminf(mn[j], __shfl_xor(mn[j], off));
      mx[j] = fmaxf(mx[j], __shfl_xor(mx[j], off));
    }
    cm += __shfl_xor(cm, off); cf += __shfl_xor(cf, off);
  }
  __shared__ float smn[4][10], smx[4][10];
  __shared__ unsigned int sc[4][2];
  int wave = tid >> 6, lane = tid & 63;
  if (lane == 0) {
    #pragma unroll
    for (int j = 0; j < 10; j++) { smn[wave][j] = mn[j]; smx[wave][j] = mx[j]; }
    sc[wave][0] = cm; sc[wave][1] = cf;
  }
  __syncthreads();
  unsigned int* out = ws + WS_A + bid * 22;
  if (tid < 10) {
    float m = fminf(fminf(smn[0][tid], smn[1][tid]), fminf(smn[2][tid], smn[3][tid]));
    out[tid] = map_f(m);
  } else if (tid < 20) {
    int j = tid - 10;
    float m = fmaxf(fmaxf(smx[0][j], smx[1][j]), fmaxf(smx[2][j], smx[3][j]));
    out[tid] = map_f(m);
  } else if (tid < 22) {
    int j = tid - 20;
    out[tid] = sc[0][j] + sc[1][j] + sc[2][j] + sc[3][j];
  }
  // block 0 zeroes the global-hist region consumed by k_hist (stream-ordered)
  if (bid == 0) {
    for (int i = tid; i < 200; i += 256) ws[WS_B + i] = 0u;
  }
}

// ------------- pass 2 over data_encoded: hist -> single global array ---------
__global__ __launch_bounds__(256) void k_hist(const float* __restrict__ enc,
                                              unsigned int* __restrict__ ws) {
  __shared__ float mnv[10], wid[10];
  __shared__ unsigned int h[200];
  int tid = threadIdx.x, bid = blockIdx.x;
  for (int i = tid; i < 200; i += 256) h[i] = 0u;
  if (tid < 10) {
    unsigned int umn = 0xFFFFFFFFu, umx = 0u;
    #pragma unroll 4
    for (int b = 0; b < 128; b++) {
      umn = min(umn, ws[WS_A + b * 22 + tid]);
      umx = max(umx, ws[WS_A + b * 22 + 10 + tid]);
    }
    float mn = unmap_f(umn);
    mnv[tid] = mn;
    wid[tid] = fmaxf(unmap_f(umx) - mn, 1e-12f);
  }
  __syncthreads();
  const float4* e4 = (const float4*)enc;
  #pragma unroll
  for (int i = 0; i < 8; i++) {
    size_t g = (size_t)bid * 2048 + i * 256 + tid;
    float4 a = e4[g * 3 + 0], b = e4[g * 3 + 1], c = e4[g * 3 + 2];
    float v[12] = {a.x,a.y,a.z,a.w,b.x,b.y,b.z,b.w,c.x,c.y,c.z,c.w};
    int base = (v[11] == 0.0f) ? 0 : ((v[11] == 1.0f) ? 100 : -1);
    if (base >= 0) {
      #pragma unroll
      for (int cc = 0; cc < 10; cc++) {
        float t = (v[cc] - mnv[cc]) / wid[cc] * 10.0f;  // reference op order
        int bi = min(max((int)floorf(t), 0), 9);
        atomicAdd(&h[base + cc * 10 + bi], 1u);
      }
    }
  }
  __syncthreads();
  if (tid < 200) atomicAdd(ws + WS_B + tid, h[tid]);   // integer: deterministic
}

// ---------------- main pass: 24 wave-streams/CU + d-prefetch ----------------
// d double-buffered in LDS via global_load_lds (4 DMA instr/tile); t in
// single-buffered registers (r0-proven, no cross-iteration carries -> no
// spill). Pipeline invariant at loop top: outstanding = d(p)[oldest 4] +
// t(cur)[4]. Issue d(p^1) -> 12; vmcnt(8) drains exactly d(p). Compiler
// auto-inserts the precise wait for the t registers before their first use.
__device__ __forceinline__ void issue_d(const float* __restrict__ d,
                                        int tile, int lane, float* bd) {
  const float4* dsp = (const float4*)d + (size_t)tile * TILE_F4;
  #pragma unroll
  for (int it = 0; it < 3; ++it)
    __builtin_amdgcn_global_load_lds(
        (const __attribute__((address_space(1))) void*)(dsp + it * 64 + lane),
        (__attribute__((address_space(3))) void*)(bd + it * 256), 16, 0, 0);
  if (lane < 6)
    __builtin_amdgcn_global_load_lds(
        (const __attribute__((address_space(1))) void*)(dsp + 192 + lane),
        (__attribute__((address_space(3))) void*)(bd + 768), 16, 0, 0);
}

__device__ __forceinline__ void load_t(const float* __restrict__ t, int tile,
                                       int lane, float4& r0, float4& r1,
                                       float4& r2, float4& r3) {
  const float4* tsp = (const float4*)t + (size_t)tile * TILE_F4;
  r0 = tsp[lane];
  r1 = tsp[64 + lane];
  r2 = tsp[128 + lane];
  r3 = tsp[192 + ((lane < 6) ? lane : 0)];   // clamped; garbage lanes unused
}

// mse/dot sweep with all-64-lane exp computed in the same pass and stored
// in place (raw d already in regs; LSE only needs exp values). ~13 trans/lane
// fully parallel vs 44 serial trans on 16 lanes (r1-validated structure).
__device__ __forceinline__ void sweep_tile(float* bd, float4 t0, float4 t1,
                                           float4 t2, float4 t3, int lane,
                                           float& mse, float& dot) {
  float4* b4 = (float4*)bd;
  float4 tvv[4] = {t0, t1, t2, t3};
  #pragma unroll
  for (int it = 0; it < 4; ++it) {
    int f = it * 64 + lane;
    if (it < 3 || lane < 6) {
      float4 xd = b4[f];
      float4 xt = tvv[it];
      int e = f * 4;
      int c = e - (e / 99) * 99;             // magic-mul const divisor
      float dv[4] = {xd.x, xd.y, xd.z, xd.w};
      float tw[4] = {xt.x, xt.y, xt.z, xt.w};
      #pragma unroll
      for (int k = 0; k < 4; k++) {
        int cc = c + k;
        if (cc >= 99) cc -= 99;
        bool cont = (cc == 0) | ((unsigned)(cc - 55) <= 2u);
        float diff = dv[k] - tw[k];
        if (cont) mse += diff * diff;
        else      dot += tw[k] * dv[k];
      }
      float4 ev;
      ev.x = __expf(xd.x); ev.y = __expf(xd.y);
      ev.z = __expf(xd.z); ev.w = __expf(xd.w);
      b4[f] = ev;
    }
  }
}

// LSE over precomputed exp: 2 lanes/row (even: blocks in cols 1..51, odd:
// cols 51..99); pure LDS reads + adds + 8 logs (r1-validated split).
__device__ __forceinline__ void lse_adds(const float* bd, int lane, float& ce) {
  if (lane < 2 * TILE_ROWS) {
    const float* row = bd + (lane >> 1) * 99;
    float Z;
    if ((lane & 1) == 0) {                // blocks (1,8)(8,24)(24,31)(31,45)(45,51)
      Z = 0.f;
      #pragma unroll
      for (int c = 1; c < 8; c++) Z += row[c];
      ce += __logf(Z);
      Z = 0.f;
      #pragma unroll
      for (int c = 8; c < 24; c++) Z += row[c];
      ce += __logf(Z);
      Z = 0.f;
      #pragma unroll
      for (int c = 24; c < 31; c++) Z += row[c];
      ce += __logf(Z);
      Z = 0.f;
      #pragma unroll
      for (int c = 31; c < 45; c++) Z += row[c];
      ce += __logf(Z);
      Z = 0.f;
      #pragma unroll
      for (int c = 45; c < 51; c++) Z += row[c];
      ce += __logf(Z);
    } else {                              // blocks (51,53)(53,55)(58,99)
      Z = 0.f;
      #pragma unroll
      for (int c = 51; c < 53; c++) Z += row[c];
      ce += __logf(Z);
      Z = 0.f;
      #pragma unroll
      for (int c = 53; c < 55; c++) Z += row[c];
      ce += __logf(Z);
      float Za = 0.f, Zb = 0.f;           // split 41-chain into 2 accumulators
      #pragma unroll
      for (int c = 58; c < 78; c++) Za += row[c];
      #pragma unroll
      for (int c = 78; c < 99; c++) Zb += row[c];
      ce += __logf(Za + Zb);
    }
  }
}

__global__ __launch_bounds__(256, 6) void k_main(const float* __restrict__ d,
                                                 const float* __restrict__ t,
                                                 unsigned int* __restrict__ ws) {
  __shared__ float sd[4][2][800];       // [wave][pingpong][800] = 25.6 KB
  __shared__ float red[12];
  int tid = threadIdx.x, bid = blockIdx.x;
  int wave = tid >> 6, lane = tid & 63;
  float* base = &sd[wave][0][0];        // ping-pong stride 800 floats

  float mse = 0.f, dot = 0.f, ce = 0.f;
  int gw = bid * 4 + wave;              // global wave stream id

  int p = 0;
  int tile = gw;
  issue_d(d, tile, lane, base);                        // d(0): oldest 4
  float4 t0, t1, t2, t3;
  load_t(t, tile, lane, t0, t1, t2, t3);               // t(0): next 4
  for (;;) {
    int nx = tile + N_STREAMS;
    bool hn = nx < N_TILES;                            // wave-uniform
    if (hn) {
      issue_d(d, nx, lane, base + (p ^ 1) * 800);      // 12 outstanding
      asm volatile("s_waitcnt vmcnt(8)" ::: "memory"); // drain d(p) only
    } else {
      asm volatile("s_waitcnt vmcnt(4)" ::: "memory"); // drain d(p); t waited by compiler
    }
    __builtin_amdgcn_sched_barrier(0);
    float* cb = base + p * 800;
    sweep_tile(cb, t0, t1, t2, t3, lane, mse, dot);    // t regs die here
    if (hn) load_t(t, nx, lane, t0, t1, t2, t3);       // reuse same reg slots
    asm volatile("s_waitcnt lgkmcnt(0)" ::: "memory"); // exp writes visible
    __builtin_amdgcn_sched_barrier(0);
    lse_adds(cb, lane, ce);                            // covers t-load latency
    if (!hn) break;
    p ^= 1;
    tile = nx;
  }

  // ---- block reduction (single barrier AFTER the streaming loop) ----
  #pragma unroll
  for (int off = 32; off; off >>= 1) {
    mse += __shfl_xor(mse, off);
    dot += __shfl_xor(dot, off);
    ce  += __shfl_xor(ce,  off);
  }
  if (lane == 0) { red[wave] = mse; red[4 + wave] = dot; red[8 + wave] = ce; }
  __syncthreads();
  if (tid == 0) {
    float* C = (float*)(ws + WS_C);
    C[bid]                   = red[0] + red[1] + red[2]  + red[3];
    C[MAIN_BLOCKS + bid]     = red[4] + red[5] + red[6]  + red[7];
    C[2 * MAIN_BLOCKS + bid] = red[8] + red[9] + red[10] + red[11];
  }
}

// ---------------- finalize ----------------
__global__ __launch_bounds__(256) void k_final(const unsigned int* __restrict__ ws,
                                               float* __restrict__ out) {
  __shared__ float h[200];
  __shared__ float part[256];
  __shared__ float red3[12];
  __shared__ float cnts[2];
  int tid = threadIdx.x;
  if (tid < 200) h[tid] = (float)ws[WS_B + tid];       // pre-reduced by k_hist
  if (tid == 200 || tid == 201) {
    unsigned int s = 0;
    #pragma unroll 4
    for (int b = 0; b < 128; b++) s += ws[WS_A + b * 22 + 20 + (tid - 200)];
    cnts[tid - 200] = fmaxf((float)s, 1.0f);
  }
  const float* C = (const float*)(ws + WS_C);
  float msum = 0.f, dsum = 0.f, csum = 0.f;
  for (int i = tid; i < MAIN_BLOCKS; i += 256) {
    msum += C[i]; dsum += C[MAIN_BLOCKS + i]; csum += C[2 * MAIN_BLOCKS + i];
  }
  #pragma unroll
  for (int off = 32; off; off >>= 1) {
    msum += __shfl_xor(msum, off);
    dsum += __shfl_xor(dsum, off);
    csum += __shfl_xor(csum, off);
  }
  int wave = tid >> 6, lane = tid & 63;
  if (lane == 0) { red3[wave] = msum; red3[4 + wave] = dsum; red3[8 + wave] = csum; }
  __syncthreads();
  float term = 0.f;
  if (tid < 100) {
    float mc = h[tid], fc = h[100 + tid];
    if (mc > 0.f && fc > 0.f) {
      float p = mc / cnts[0];
      float q = fc / cnts[1];
      term = p * logf(p / q);
    }
  }
  part[tid] = term;
  __syncthreads();
  for (int s = 128; s; s >>= 1) {
    if (tid < s) part[tid] += part[tid + s];
    __syncthreads();
  }
  if (tid == 0) {
    const float invB = 1.0f / (float)B_ROWS;
    float mse = (red3[0] + red3[1] + red3[2] + red3[3]) * invB;
    float dd  = (red3[4] + red3[5] + red3[6] + red3[7]);
    float cc  = (red3[8] + red3[9] + red3[10] + red3[11]);
    float ce  = (cc - dd) * invB;
    float akld = 0.5f * part[0];
    out[0] = 0.5f * (mse + ce) + akld;
    out[1] = mse;
    out[2] = ce;
    out[3] = akld;
  }
}

extern "C" void kernel_launch(void* const* d_in, const int* in_sizes, int n_in,
                              void* d_out, int out_size, void* d_ws, size_t ws_size,
                              hipStream_t stream) {
  const float* enc = (const float*)d_in[0];   // data_encoded (B,12)
  const float* dec = (const float*)d_in[1];   // data_decoded (B,99)
  const float* tru = (const float*)d_in[2];   // data_true    (B,99)
  unsigned int* ws = (unsigned int*)d_ws;
  float* out = (float*)d_out;

  hipLaunchKernelGGL(k_minmax, dim3(128),         dim3(256), 0, stream, enc, ws);
  hipLaunchKernelGGL(k_hist,   dim3(128),         dim3(256), 0, stream, enc, ws);
  hipLaunchKernelGGL(k_main,   dim3(MAIN_BLOCKS), dim3(256), 0, stream, dec, tru, ws);
  hipLaunchKernelGGL(k_final,  dim3(1),           dim3(256), 0, stream, ws, out);
}